// Round 7
// baseline (591.787 us; speedup 1.0000x reference)
//
#include <hip/hip_runtime.h>

#define NN 100000
#define NE 3200000
#define INCH 200
#define HID 64
#define NG 500
#define SH 7
#define BCOLS 128
#define NB 782      // ceil(NN / BCOLS)
#define BSLOT 4608  // fixed slots per bucket (mean 4096, ~8 sigma margin)

typedef unsigned long long u64;

// ---------------- partition edges into fixed bucket regions ----------------
__global__ __launch_bounds__(256) void k_part(const int* __restrict__ ei,
                                              const float* __restrict__ attr,
                                              int* __restrict__ gcur,
                                              u64* __restrict__ epay) {
  __shared__ int hist[NB];
  __shared__ int base[NB];
  int tid = threadIdx.x;
  for (int i = tid; i < NB; i += 256) hist[i] = 0;
  __syncthreads();
  int eb = blockIdx.x * 8192;
  int cols[32];
  for (int i = 0; i < 32; ++i) {
    int e = eb + i * 256 + tid;
    int c = (e < NE) ? ei[NE + e] : -1;
    cols[i] = c;
    if (c >= 0) atomicAdd(&hist[c >> SH], 1);
  }
  __syncthreads();
  for (int i = tid; i < NB; i += 256) {
    int v = hist[i];
    base[i] = v ? (atomicAdd(&gcur[i], v) + i * BSLOT) : 0;
    hist[i] = 0;
  }
  __syncthreads();
  for (int i = 0; i < 32; ++i) {
    int c = cols[i];
    if (c >= 0) {
      int e = eb + i * 256 + tid;
      int r = ei[e];
      float w = fabsf(attr[e]);
      int b = c >> SH;
      int loc = atomicAdd(&hist[b], 1);
      unsigned int lo = (unsigned int)r | ((unsigned int)(c & (BCOLS - 1)) << 20);
      epay[base[b] + loc] = ((u64)__float_as_uint(w) << 32) | lo;
    }
  }
}

// ---------------- per-bucket counting sort (LDS-staged) -> sorted payload + offs/ends + dinv ----------------
__global__ __launch_bounds__(256) void k_sort(const u64* __restrict__ epay,
                                              const int* __restrict__ gcur,
                                              u64* __restrict__ epay2,
                                              int* __restrict__ offs,
                                              int* __restrict__ ends,
                                              float* __restrict__ dinv) {
  __shared__ float ws[BCOLS];
  __shared__ int cnt[BCOLS];
  __shared__ int cur[BCOLS];
  __shared__ u64 stg[BSLOT];   // 36.8 KB staged sorted bucket
  int b = blockIdx.x, tid = threadIdx.x;
  if (tid < BCOLS) { ws[tid] = 0.f; cnt[tid] = 0; }
  __syncthreads();
  int n = gcur[b];
  int e0 = b * BSLOT;
  for (int i = tid; i < n; i += 256) {
    u64 p = epay[e0 + i];
    float w = __uint_as_float((unsigned int)(p >> 32));
    int c7 = ((unsigned int)p >> 20) & (BCOLS - 1);
    atomicAdd(&cnt[c7], 1);
    atomicAdd(&ws[c7], w);
  }
  __syncthreads();
  if (tid < 64) {  // exclusive scan of cnt[128] on wave 0
    int a0 = cnt[tid * 2], a1 = cnt[tid * 2 + 1];
    int s = a0 + a1;
    int t = s;
    #pragma unroll
    for (int d = 1; d < 64; d <<= 1) { int u = __shfl_up(t, d); if (tid >= d) t += u; }
    int excl = t - s;
    cur[tid * 2] = excl;
    cur[tid * 2 + 1] = excl + a0;
  }
  __syncthreads();
  if (tid < BCOLS) {
    int node = b * BCOLS + tid;
    if (node < NN) {
      int st = e0 + cur[tid];
      offs[node] = st;
      ends[node] = st + cnt[tid];
      dinv[node] = 1.0f / sqrtf(ws[tid] + 1.0f);
    }
  }
  __syncthreads();
  // scatter into LDS (node-sorted within bucket)
  for (int i = tid; i < n; i += 256) {
    u64 p = epay[e0 + i];
    int c7 = ((unsigned int)p >> 20) & (BCOLS - 1);
    int loc = atomicAdd(&cur[c7], 1);
    stg[loc] = (p & 0xFFFFFFFF00000000ull) | ((unsigned int)p & 0xFFFFF);
  }
  __syncthreads();
  // coalesced flush
  for (int i = tid; i < n; i += 256) epay2[e0 + i] = stg[i];
}

// ---------------- fp32 GEMM (128-node blocks) with dinv-scaled output ----------------
__global__ __launch_bounds__(256) void k_gemm(const float* __restrict__ A,
                                              const float* __restrict__ B,
                                              float* __restrict__ C, int M, int K,
                                              const float* __restrict__ dscale) {
  __shared__ float As[8][128];
  __shared__ float Bs[8][64];
  int tid = threadIdx.x;
  int ng = tid >> 4;      // 0..15 -> 8 nodes each
  int cg = tid & 15;      // 0..15 -> 4 cols each
  int nbase = blockIdx.x * 128;
  float acc[8][4];
  #pragma unroll
  for (int i = 0; i < 8; i++)
    #pragma unroll
    for (int j = 0; j < 4; j++) acc[i][j] = 0.f;

  int arow = nbase + (tid >> 1);
  int acl = (tid & 1) * 4;
  int ar = arow < M ? arow : M - 1;

  for (int k0 = 0; k0 < K; k0 += 8) {
    float4 av = *(const float4*)(A + (size_t)ar * K + k0 + acl);
    float2 bv = ((const float2*)(B + (size_t)k0 * 64))[tid];
    __syncthreads();
    As[acl + 0][tid >> 1] = av.x;
    As[acl + 1][tid >> 1] = av.y;
    As[acl + 2][tid >> 1] = av.z;
    As[acl + 3][tid >> 1] = av.w;
    ((float2*)Bs)[tid] = bv;
    __syncthreads();
    #pragma unroll
    for (int k = 0; k < 8; k++) {
      float a[8], bb[4];
      *(float4*)(a)     = *(const float4*)&As[k][ng * 8];
      *(float4*)(a + 4) = *(const float4*)&As[k][ng * 8 + 4];
      *(float4*)(bb)    = *(const float4*)&Bs[k][cg * 4];
      #pragma unroll
      for (int i = 0; i < 8; i++)
        #pragma unroll
        for (int j = 0; j < 4; j++) acc[i][j] += a[i] * bb[j];
    }
  }
  #pragma unroll
  for (int i = 0; i < 8; i++) {
    int n = nbase + ng * 8 + i;
    if (n < M) {
      float dv = dscale[n];
      *(float4*)(C + (size_t)n * 64 + cg * 4) =
        make_float4(acc[i][0] * dv, acc[i][1] * dv, acc[i][2] * dv, acc[i][3] * dv);
    }
  }
}

// ---------------- layer-1 aggregation fused with gemm2: writes g2 = dinv .* (h1 @ W2) ----------------
__global__ __launch_bounds__(256) void k_agg1(const float* __restrict__ g,
                                              const int* __restrict__ offs,
                                              const int* __restrict__ ends,
                                              const u64* __restrict__ epay2,
                                              const float* __restrict__ dinv,
                                              const float* __restrict__ b1,
                                              const float* __restrict__ W2,
                                              float* __restrict__ g2out) {
  __shared__ float W2T[64 * 65];   // W2T[j*65+k] = W2[k][j]; bank (j+k)%32 -> conflict-free
  __shared__ float h1s[4][64];
  int tid = threadIdx.x;
  for (int idx = tid; idx < 4096; idx += 256) {
    int k = idx >> 6, j = idx & 63;
    W2T[j * 65 + k] = W2[idx];
  }
  __syncthreads();
  int wid = tid >> 6;
  int node = blockIdx.x * 4 + wid;
  int lane = tid & 63;
  int e0 = offs[node], e1 = ends[node];
  float acc = 0.f;
  int e = e0;
  for (; e + 8 <= e1; e += 8) {
    u64 p0 = epay2[e],     p1 = epay2[e + 1];
    u64 p2 = epay2[e + 2], p3 = epay2[e + 3];
    u64 p4 = epay2[e + 4], p5 = epay2[e + 5];
    u64 p6 = epay2[e + 6], p7 = epay2[e + 7];
    float g0 = g[(size_t)((unsigned int)p0 & 0xFFFFF) * 64 + lane];
    float g1 = g[(size_t)((unsigned int)p1 & 0xFFFFF) * 64 + lane];
    float g2 = g[(size_t)((unsigned int)p2 & 0xFFFFF) * 64 + lane];
    float g3 = g[(size_t)((unsigned int)p3 & 0xFFFFF) * 64 + lane];
    float g4 = g[(size_t)((unsigned int)p4 & 0xFFFFF) * 64 + lane];
    float g5 = g[(size_t)((unsigned int)p5 & 0xFFFFF) * 64 + lane];
    float g6 = g[(size_t)((unsigned int)p6 & 0xFFFFF) * 64 + lane];
    float g7 = g[(size_t)((unsigned int)p7 & 0xFFFFF) * 64 + lane];
    acc += __uint_as_float((unsigned int)(p0 >> 32)) * g0;
    acc += __uint_as_float((unsigned int)(p1 >> 32)) * g1;
    acc += __uint_as_float((unsigned int)(p2 >> 32)) * g2;
    acc += __uint_as_float((unsigned int)(p3 >> 32)) * g3;
    acc += __uint_as_float((unsigned int)(p4 >> 32)) * g4;
    acc += __uint_as_float((unsigned int)(p5 >> 32)) * g5;
    acc += __uint_as_float((unsigned int)(p6 >> 32)) * g6;
    acc += __uint_as_float((unsigned int)(p7 >> 32)) * g7;
  }
  for (; e < e1; ++e) {
    u64 p = epay2[e];
    int r = (unsigned int)p & 0xFFFFF;
    acc += __uint_as_float((unsigned int)(p >> 32)) * g[(size_t)r * 64 + lane];
  }
  float dv = dinv[node];
  float h1 = fmaxf((acc + g[(size_t)node * 64 + lane]) * dv + b1[lane], 0.f);
  h1s[wid][lane] = h1;  // wave-local write->read, in-order wave, no barrier needed
  float a2 = 0.f;
  const float* wrow = &W2T[lane * 65];
  #pragma unroll
  for (int k = 0; k < 64; ++k) a2 += h1s[wid][k] * wrow[k];
  g2out[(size_t)node * 64 + lane] = a2 * dv;
}

// ---------------- layer-2 aggregation fused with mean-pool accumulate ----------------
__global__ void k_agg2(const float* __restrict__ g,
                       const int* __restrict__ offs,
                       const int* __restrict__ ends,
                       const u64* __restrict__ epay2,
                       const float* __restrict__ dinv,
                       const float* __restrict__ b2,
                       const int* __restrict__ batch,
                       float* __restrict__ pooled) {
  int node = blockIdx.x * 4 + (threadIdx.x >> 6);
  int lane = threadIdx.x & 63;
  int e0 = offs[node], e1 = ends[node];
  float acc = 0.f;
  int e = e0;
  for (; e + 8 <= e1; e += 8) {
    u64 p0 = epay2[e],     p1 = epay2[e + 1];
    u64 p2 = epay2[e + 2], p3 = epay2[e + 3];
    u64 p4 = epay2[e + 4], p5 = epay2[e + 5];
    u64 p6 = epay2[e + 6], p7 = epay2[e + 7];
    float g0 = g[(size_t)((unsigned int)p0 & 0xFFFFF) * 64 + lane];
    float g1 = g[(size_t)((unsigned int)p1 & 0xFFFFF) * 64 + lane];
    float g2 = g[(size_t)((unsigned int)p2 & 0xFFFFF) * 64 + lane];
    float g3 = g[(size_t)((unsigned int)p3 & 0xFFFFF) * 64 + lane];
    float g4 = g[(size_t)((unsigned int)p4 & 0xFFFFF) * 64 + lane];
    float g5 = g[(size_t)((unsigned int)p5 & 0xFFFFF) * 64 + lane];
    float g6 = g[(size_t)((unsigned int)p6 & 0xFFFFF) * 64 + lane];
    float g7 = g[(size_t)((unsigned int)p7 & 0xFFFFF) * 64 + lane];
    acc += __uint_as_float((unsigned int)(p0 >> 32)) * g0;
    acc += __uint_as_float((unsigned int)(p1 >> 32)) * g1;
    acc += __uint_as_float((unsigned int)(p2 >> 32)) * g2;
    acc += __uint_as_float((unsigned int)(p3 >> 32)) * g3;
    acc += __uint_as_float((unsigned int)(p4 >> 32)) * g4;
    acc += __uint_as_float((unsigned int)(p5 >> 32)) * g5;
    acc += __uint_as_float((unsigned int)(p6 >> 32)) * g6;
    acc += __uint_as_float((unsigned int)(p7 >> 32)) * g7;
  }
  for (; e < e1; ++e) {
    u64 p = epay2[e];
    int r = (unsigned int)p & 0xFFFFF;
    acc += __uint_as_float((unsigned int)(p >> 32)) * g[(size_t)r * 64 + lane];
  }
  float v = fmaxf((acc + g[(size_t)node * 64 + lane]) * dinv[node] + b2[lane], 0.f);
  atomicAdd(&pooled[batch[node] * 64 + lane], v);
}

// ---------------- MLP head: one block per graph; count via binary search on sorted batch ----------------
__global__ __launch_bounds__(256) void k_mlp(const float* __restrict__ pooled,
                                             const int* __restrict__ batch,
                                             const float* __restrict__ L1, const float* __restrict__ c1,
                                             const float* __restrict__ L2, const float* __restrict__ c2,
                                             float* __restrict__ out) {
  __shared__ float m[64];
  __shared__ float xf[200];
  __shared__ float red[8];
  __shared__ float cnts;
  int g = blockIdx.x, tid = threadIdx.x;
  if (tid == 0) {
    int lo = 0, hi = NN;
    while (lo < hi) { int mid = (lo + hi) >> 1; if (batch[mid] < g) lo = mid + 1; else hi = mid; }
    int l0 = lo;
    hi = NN;
    while (lo < hi) { int mid = (lo + hi) >> 1; if (batch[mid] < g + 1) lo = mid + 1; else hi = mid; }
    cnts = fmaxf((float)(lo - l0), 1.f);
  }
  __syncthreads();
  if (tid < 64) m[tid] = pooled[g * 64 + tid] / cnts;
  __syncthreads();
  if (tid < 200) {
    float a = c1[tid];
    #pragma unroll
    for (int k = 0; k < 64; k++) a += m[k] * L1[k * 200 + tid];
    xf[tid] = fmaxf(a, 0.f);
  }
  __syncthreads();
  float p0 = 0.f, p1 = 0.f;
  if (tid < 200) {
    float v = xf[tid];
    p0 = v * L2[tid * 2];
    p1 = v * L2[tid * 2 + 1];
  }
  #pragma unroll
  for (int d = 32; d > 0; d >>= 1) { p0 += __shfl_down(p0, d); p1 += __shfl_down(p1, d); }
  int lane = tid & 63, wid = tid >> 6;
  if (lane == 0) { red[wid * 2] = p0; red[wid * 2 + 1] = p1; }
  __syncthreads();
  if (tid == 0) {
    out[g * 2 + 0] = red[0] + red[2] + red[4] + red[6] + c2[0];
    out[g * 2 + 1] = red[1] + red[3] + red[5] + red[7] + c2[1];
  }
}

// ---------------- launch ----------------
extern "C" void kernel_launch(void* const* d_in, const int* in_sizes, int n_in,
                              void* d_out, int out_size, void* d_ws, size_t ws_size,
                              hipStream_t stream) {
  (void)in_sizes; (void)n_in; (void)out_size; (void)ws_size;
  const float* x    = (const float*)d_in[0];
  const int*   ei   = (const int*)d_in[1];
  const float* attr = (const float*)d_in[2];
  const int*   batch= (const int*)d_in[3];
  const float* W1   = (const float*)d_in[4];
  const float* b1   = (const float*)d_in[5];
  const float* W2   = (const float*)d_in[6];
  const float* b2   = (const float*)d_in[7];
  const float* L1   = (const float*)d_in[8];
  const float* c1   = (const float*)d_in[9];
  const float* L2   = (const float*)d_in[10];
  const float* c2   = (const float*)d_in[11];
  float* out = (float*)d_out;

  char* p = (char*)d_ws;
  auto alloc = [&](size_t bytes) -> void* {
    void* r = (void*)p;
    p += (bytes + 511) & ~(size_t)511;
    return r;
  };
  // epay (bucket regions, dead after k_sort) aliases bufA (first written by k_gemm)
  u64* epay = (u64*)alloc((size_t)NB * BSLOT * 8);   // 28.8 MB
  float* bufA = (float*)epay;                        // alias (needs 25.6 MB)
  u64* epay2 = (u64*)alloc((size_t)NB * BSLOT * 8);  // 28.8 MB
  float* bufB   = (float*)alloc((size_t)NN * 64 * 4);
  int*   offs   = (int*)alloc((size_t)NN * 4);
  int*   ends   = (int*)alloc((size_t)NN * 4);
  float* dinv   = (float*)alloc((size_t)NN * 4);
  int*   gcur   = (int*)alloc((size_t)NB * 4);       // | contiguous zero region
  float* pooled = (float*)alloc((size_t)NG * 64 * 4);// |

  size_t zspan = (size_t)((char*)pooled + (size_t)NG * 64 * 4 - (char*)gcur);
  hipMemsetAsync(gcur, 0, zspan, stream);

  // build: bucket partition (fixed regions) + per-bucket counting sort
  k_part<<<391, 256, 0, stream>>>(ei, attr, gcur, epay);
  k_sort<<<NB, 256, 0, stream>>>(epay, gcur, epay2, offs, ends, dinv);

  // layer 1: g1 = dinv .* (x @ W1); agg1 fused with gemm2 -> bufB = g2
  k_gemm<<<782, 256, 0, stream>>>(x, W1, bufA, NN, INCH, dinv);
  k_agg1<<<NN / 4, 256, 0, stream>>>(bufA, offs, ends, epay2, dinv, b1, W2, bufB);
  // layer 2: agg fused with pooling accumulate
  k_agg2<<<NN / 4, 256, 0, stream>>>(bufB, offs, ends, epay2, dinv, b2, batch, pooled);

  // head
  k_mlp<<<NG, 256, 0, stream>>>(pooled, batch, L1, c1, L2, c2, out);
}

// Round 8
// 543.181 us; speedup vs baseline: 1.0895x; 1.0895x over previous
//
#include <hip/hip_runtime.h>

#define NN 100000
#define NE 3200000
#define INCH 200
#define HID 64
#define NG 500
#define SH 7
#define BCOLS 128
#define NB 782      // ceil(NN / BCOLS)
#define BSLOT 4608  // fixed slots per bucket (mean 4092, ~8 sigma margin)

typedef unsigned long long u64;
typedef unsigned short u16;
typedef unsigned int u32;

__device__ __forceinline__ float bf2f(u16 v) { return __uint_as_float(((u32)v) << 16); }
__device__ __forceinline__ u16 f2bf(float f) {
  u32 u = __float_as_uint(f);
  u += 0x7FFF + ((u >> 16) & 1);   // round-nearest-even
  return (u16)(u >> 16);
}

// ---------------- partition edges into fixed bucket regions ----------------
__global__ __launch_bounds__(256) void k_part(const int* __restrict__ ei,
                                              const float* __restrict__ attr,
                                              int* __restrict__ gcur,
                                              u64* __restrict__ epay) {
  __shared__ int hist[NB];
  __shared__ int base[NB];
  int tid = threadIdx.x;
  for (int i = tid; i < NB; i += 256) hist[i] = 0;
  __syncthreads();
  int eb = blockIdx.x * 8192;
  int cols[32];
  for (int i = 0; i < 32; ++i) {
    int e = eb + i * 256 + tid;
    int c = (e < NE) ? ei[NE + e] : -1;
    cols[i] = c;
    if (c >= 0) atomicAdd(&hist[c >> SH], 1);
  }
  __syncthreads();
  for (int i = tid; i < NB; i += 256) {
    int v = hist[i];
    base[i] = v ? (atomicAdd(&gcur[i], v) + i * BSLOT) : 0;
    hist[i] = 0;
  }
  __syncthreads();
  for (int i = 0; i < 32; ++i) {
    int c = cols[i];
    if (c >= 0) {
      int e = eb + i * 256 + tid;
      int r = ei[e];
      float w = fabsf(attr[e]);
      int b = c >> SH;
      int loc = atomicAdd(&hist[b], 1);
      u32 lo = (u32)r | ((u32)(c & (BCOLS - 1)) << 20);
      epay[base[b] + loc] = ((u64)__float_as_uint(w) << 32) | lo;
    }
  }
}

// ---------------- per-bucket counting sort (LDS-staged) -> sorted payload + offs/ends + dinv ----------------
__global__ __launch_bounds__(256) void k_sort(const u64* __restrict__ epay,
                                              const int* __restrict__ gcur,
                                              u64* __restrict__ epay2,
                                              int* __restrict__ offs,
                                              int* __restrict__ ends,
                                              float* __restrict__ dinv) {
  __shared__ float ws[BCOLS];
  __shared__ int cnt[BCOLS];
  __shared__ int cur[BCOLS];
  __shared__ u64 stg[BSLOT];   // 36.8 KB staged sorted bucket
  int b = blockIdx.x, tid = threadIdx.x;
  if (tid < BCOLS) { ws[tid] = 0.f; cnt[tid] = 0; }
  __syncthreads();
  int n = gcur[b];
  int e0 = b * BSLOT;
  for (int i = tid; i < n; i += 256) {
    u64 p = epay[e0 + i];
    float w = __uint_as_float((u32)(p >> 32));
    int c7 = ((u32)p >> 20) & (BCOLS - 1);
    atomicAdd(&cnt[c7], 1);
    atomicAdd(&ws[c7], w);
  }
  __syncthreads();
  if (tid < 64) {  // exclusive scan of cnt[128] on wave 0
    int a0 = cnt[tid * 2], a1 = cnt[tid * 2 + 1];
    int s = a0 + a1;
    int t = s;
    #pragma unroll
    for (int d = 1; d < 64; d <<= 1) { int u = __shfl_up(t, d); if (tid >= d) t += u; }
    int excl = t - s;
    cur[tid * 2] = excl;
    cur[tid * 2 + 1] = excl + a0;
  }
  __syncthreads();
  if (tid < BCOLS) {
    int node = b * BCOLS + tid;
    if (node < NN) {
      int st = e0 + cur[tid];
      offs[node] = st;
      ends[node] = st + cnt[tid];
      dinv[node] = 1.0f / sqrtf(ws[tid] + 1.0f);
    }
  }
  __syncthreads();
  // scatter into LDS (node-sorted within bucket)
  for (int i = tid; i < n; i += 256) {
    u64 p = epay[e0 + i];
    int c7 = ((u32)p >> 20) & (BCOLS - 1);
    int loc = atomicAdd(&cur[c7], 1);
    stg[loc] = (p & 0xFFFFFFFF00000000ull) | ((u32)p & 0xFFFFF);
  }
  __syncthreads();
  // coalesced flush
  for (int i = tid; i < n; i += 256) epay2[e0 + i] = stg[i];
}

// ---------------- fp32 GEMM (128-node blocks), bf16 output scaled by dinv ----------------
__global__ __launch_bounds__(256) void k_gemm(const float* __restrict__ A,
                                              const float* __restrict__ B,
                                              u16* __restrict__ C, int M, int K,
                                              const float* __restrict__ dscale) {
  __shared__ float As[8][128];
  __shared__ float Bs[8][64];
  int tid = threadIdx.x;
  int ng = tid >> 4;      // 0..15 -> 8 nodes each
  int cg = tid & 15;      // 0..15 -> 4 cols each
  int nbase = blockIdx.x * 128;
  float acc[8][4];
  #pragma unroll
  for (int i = 0; i < 8; i++)
    #pragma unroll
    for (int j = 0; j < 4; j++) acc[i][j] = 0.f;

  int arow = nbase + (tid >> 1);
  int acl = (tid & 1) * 4;
  int ar = arow < M ? arow : M - 1;

  for (int k0 = 0; k0 < K; k0 += 8) {
    float4 av = *(const float4*)(A + (size_t)ar * K + k0 + acl);
    float2 bv = ((const float2*)(B + (size_t)k0 * 64))[tid];
    __syncthreads();
    As[acl + 0][tid >> 1] = av.x;
    As[acl + 1][tid >> 1] = av.y;
    As[acl + 2][tid >> 1] = av.z;
    As[acl + 3][tid >> 1] = av.w;
    ((float2*)Bs)[tid] = bv;
    __syncthreads();
    #pragma unroll
    for (int k = 0; k < 8; k++) {
      float a[8], bb[4];
      *(float4*)(a)     = *(const float4*)&As[k][ng * 8];
      *(float4*)(a + 4) = *(const float4*)&As[k][ng * 8 + 4];
      *(float4*)(bb)    = *(const float4*)&Bs[k][cg * 4];
      #pragma unroll
      for (int i = 0; i < 8; i++)
        #pragma unroll
        for (int j = 0; j < 4; j++) acc[i][j] += a[i] * bb[j];
    }
  }
  #pragma unroll
  for (int i = 0; i < 8; i++) {
    int n = nbase + ng * 8 + i;
    if (n < M) {
      float dv = dscale[n];
      ushort4 o;
      o.x = f2bf(acc[i][0] * dv);
      o.y = f2bf(acc[i][1] * dv);
      o.z = f2bf(acc[i][2] * dv);
      o.w = f2bf(acc[i][3] * dv);
      *(ushort4*)(C + (size_t)n * 64 + cg * 4) = o;
    }
  }
}

// ---------------- CSR aggregation over bf16 g; POOL=0 -> fp32 out, POOL=1 -> pooled atomics ----------------
template<int POOL>
__global__ void k_agg(const u16* __restrict__ g, const int* __restrict__ offs,
                      const int* __restrict__ ends,
                      const u64* __restrict__ epay2,
                      const float* __restrict__ dinv, const float* __restrict__ bias,
                      const int* __restrict__ batch,
                      float* __restrict__ outp) {
  int node = blockIdx.x * 4 + (threadIdx.x >> 6);
  int lane = threadIdx.x & 63;
  int e0 = offs[node], e1 = ends[node];
  float acc = 0.f;
  int e = e0;
  for (; e + 8 <= e1; e += 8) {
    u64 p0 = epay2[e],     p1 = epay2[e + 1];
    u64 p2 = epay2[e + 2], p3 = epay2[e + 3];
    u64 p4 = epay2[e + 4], p5 = epay2[e + 5];
    u64 p6 = epay2[e + 6], p7 = epay2[e + 7];
    u16 v0 = g[(size_t)((u32)p0 & 0xFFFFF) * 64 + lane];
    u16 v1 = g[(size_t)((u32)p1 & 0xFFFFF) * 64 + lane];
    u16 v2 = g[(size_t)((u32)p2 & 0xFFFFF) * 64 + lane];
    u16 v3 = g[(size_t)((u32)p3 & 0xFFFFF) * 64 + lane];
    u16 v4 = g[(size_t)((u32)p4 & 0xFFFFF) * 64 + lane];
    u16 v5 = g[(size_t)((u32)p5 & 0xFFFFF) * 64 + lane];
    u16 v6 = g[(size_t)((u32)p6 & 0xFFFFF) * 64 + lane];
    u16 v7 = g[(size_t)((u32)p7 & 0xFFFFF) * 64 + lane];
    acc += __uint_as_float((u32)(p0 >> 32)) * bf2f(v0);
    acc += __uint_as_float((u32)(p1 >> 32)) * bf2f(v1);
    acc += __uint_as_float((u32)(p2 >> 32)) * bf2f(v2);
    acc += __uint_as_float((u32)(p3 >> 32)) * bf2f(v3);
    acc += __uint_as_float((u32)(p4 >> 32)) * bf2f(v4);
    acc += __uint_as_float((u32)(p5 >> 32)) * bf2f(v5);
    acc += __uint_as_float((u32)(p6 >> 32)) * bf2f(v6);
    acc += __uint_as_float((u32)(p7 >> 32)) * bf2f(v7);
  }
  for (; e < e1; ++e) {
    u64 p = epay2[e];
    int r = (u32)p & 0xFFFFF;
    acc += __uint_as_float((u32)(p >> 32)) * bf2f(g[(size_t)r * 64 + lane]);
  }
  float v = (acc + bf2f(g[(size_t)node * 64 + lane])) * dinv[node] + bias[lane];
  v = fmaxf(v, 0.f);
  if (POOL) {
    atomicAdd(&outp[batch[node] * 64 + lane], v);
  } else {
    outp[(size_t)node * 64 + lane] = v;
  }
}

// ---------------- MLP head: one block per graph; count via binary search on sorted batch ----------------
__global__ __launch_bounds__(256) void k_mlp(const float* __restrict__ pooled,
                                             const int* __restrict__ batch,
                                             const float* __restrict__ L1, const float* __restrict__ c1,
                                             const float* __restrict__ L2, const float* __restrict__ c2,
                                             float* __restrict__ out) {
  __shared__ float m[64];
  __shared__ float xf[200];
  __shared__ float red[8];
  __shared__ float cnts;
  int g = blockIdx.x, tid = threadIdx.x;
  if (tid == 0) {
    int lo = 0, hi = NN;
    while (lo < hi) { int mid = (lo + hi) >> 1; if (batch[mid] < g) lo = mid + 1; else hi = mid; }
    int l0 = lo;
    hi = NN;
    while (lo < hi) { int mid = (lo + hi) >> 1; if (batch[mid] < g + 1) lo = mid + 1; else hi = mid; }
    cnts = fmaxf((float)(lo - l0), 1.f);
  }
  __syncthreads();
  if (tid < 64) m[tid] = pooled[g * 64 + tid] / cnts;
  __syncthreads();
  if (tid < 200) {
    float a = c1[tid];
    #pragma unroll
    for (int k = 0; k < 64; k++) a += m[k] * L1[k * 200 + tid];
    xf[tid] = fmaxf(a, 0.f);
  }
  __syncthreads();
  float p0 = 0.f, p1 = 0.f;
  if (tid < 200) {
    float v = xf[tid];
    p0 = v * L2[tid * 2];
    p1 = v * L2[tid * 2 + 1];
  }
  #pragma unroll
  for (int d = 32; d > 0; d >>= 1) { p0 += __shfl_down(p0, d); p1 += __shfl_down(p1, d); }
  int lane = tid & 63, wid = tid >> 6;
  if (lane == 0) { red[wid * 2] = p0; red[wid * 2 + 1] = p1; }
  __syncthreads();
  if (tid == 0) {
    out[g * 2 + 0] = red[0] + red[2] + red[4] + red[6] + c2[0];
    out[g * 2 + 1] = red[1] + red[3] + red[5] + red[7] + c2[1];
  }
}

// ---------------- launch ----------------
extern "C" void kernel_launch(void* const* d_in, const int* in_sizes, int n_in,
                              void* d_out, int out_size, void* d_ws, size_t ws_size,
                              hipStream_t stream) {
  (void)in_sizes; (void)n_in; (void)out_size; (void)ws_size;
  const float* x    = (const float*)d_in[0];
  const int*   ei   = (const int*)d_in[1];
  const float* attr = (const float*)d_in[2];
  const int*   batch= (const int*)d_in[3];
  const float* W1   = (const float*)d_in[4];
  const float* b1   = (const float*)d_in[5];
  const float* W2   = (const float*)d_in[6];
  const float* b2   = (const float*)d_in[7];
  const float* L1   = (const float*)d_in[8];
  const float* c1   = (const float*)d_in[9];
  const float* L2   = (const float*)d_in[10];
  const float* c2   = (const float*)d_in[11];
  float* out = (float*)d_out;

  char* p = (char*)d_ws;
  auto alloc = [&](size_t bytes) -> void* {
    void* r = (void*)p;
    p += (bytes + 511) & ~(size_t)511;
    return r;
  };
  // epay (bucket regions, dead after k_sort) aliases g1b (bf16, first written by k_gemm)
  u64* epay = (u64*)alloc((size_t)NB * BSLOT * 8);   // 28.8 MB
  u16* g1b  = (u16*)epay;                            // alias (needs 12.8 MB)
  u64* epay2 = (u64*)alloc((size_t)NB * BSLOT * 8);  // 28.8 MB
  float* h1   = (float*)alloc((size_t)NN * 64 * 4);  // fp32 h1
  u16*   g2b  = (u16*)alloc((size_t)NN * 64 * 2);    // bf16 g2
  int*   offs = (int*)alloc((size_t)NN * 4);
  int*   ends = (int*)alloc((size_t)NN * 4);
  float* dinv = (float*)alloc((size_t)NN * 4);
  int*   gcur = (int*)alloc((size_t)NB * 4);         // | contiguous zero region
  float* pooled = (float*)alloc((size_t)NG * 64 * 4);// |

  size_t zspan = (size_t)((char*)pooled + (size_t)NG * 64 * 4 - (char*)gcur);
  hipMemsetAsync(gcur, 0, zspan, stream);

  // build: bucket partition (fixed regions) + per-bucket counting sort
  k_part<<<391, 256, 0, stream>>>(ei, attr, gcur, epay);
  k_sort<<<NB, 256, 0, stream>>>(epay, gcur, epay2, offs, ends, dinv);

  // layer 1: g1 = bf16(dinv .* (x @ W1)); h1 = relu(dinv_c*(sum w*g1[r] + g1[c]) + b1)
  k_gemm<<<782, 256, 0, stream>>>(x, W1, g1b, NN, INCH, dinv);
  k_agg<0><<<NN / 4, 256, 0, stream>>>(g1b, offs, ends, epay2, dinv, b1, batch, h1);
  // layer 2: g2 = bf16(dinv .* (h1 @ W2)); agg fused with pooling accumulate
  k_gemm<<<782, 256, 0, stream>>>(h1, W2, g2b, NN, HID, dinv);
  k_agg<1><<<NN / 4, 256, 0, stream>>>(g2b, offs, ends, epay2, dinv, b2, batch, pooled);

  // head
  k_mlp<<<NG, 256, 0, stream>>>(pooled, batch, L1, c1, L2, c2, out);
}

// Round 9
// 540.515 us; speedup vs baseline: 1.0949x; 1.0049x over previous
//
#include <hip/hip_runtime.h>

#define NN 100000
#define NE 3200000
#define INCH 200
#define HID 64
#define NG 500
#define SH 7
#define BCOLS 128
#define NB 782      // ceil(NN / BCOLS)
#define BSLOT 4608  // fixed slots per bucket (mean 4092, ~8 sigma margin)

typedef unsigned long long u64;
typedef unsigned short u16;
typedef unsigned int u32;

__device__ __forceinline__ float bf2f(u16 v) { return __uint_as_float(((u32)v) << 16); }
__device__ __forceinline__ u16 f2bf(float f) {
  u32 u = __float_as_uint(f);
  u += 0x7FFF + ((u >> 16) & 1);   // round-nearest-even
  return (u16)(u >> 16);
}

// ---------------- partition edges into fixed bucket regions ----------------
__global__ __launch_bounds__(256) void k_part(const int* __restrict__ ei,
                                              const float* __restrict__ attr,
                                              int* __restrict__ gcur,
                                              u64* __restrict__ epay) {
  __shared__ int hist[NB];
  __shared__ int base[NB];
  int tid = threadIdx.x;
  for (int i = tid; i < NB; i += 256) hist[i] = 0;
  __syncthreads();
  int eb = blockIdx.x * 8192;
  int cols[32];
  for (int i = 0; i < 32; ++i) {
    int e = eb + i * 256 + tid;
    int c = (e < NE) ? ei[NE + e] : -1;
    cols[i] = c;
    if (c >= 0) atomicAdd(&hist[c >> SH], 1);
  }
  __syncthreads();
  for (int i = tid; i < NB; i += 256) {
    int v = hist[i];
    base[i] = v ? (atomicAdd(&gcur[i], v) + i * BSLOT) : 0;
    hist[i] = 0;
  }
  __syncthreads();
  for (int i = 0; i < 32; ++i) {
    int c = cols[i];
    if (c >= 0) {
      int e = eb + i * 256 + tid;
      int r = ei[e];
      float w = fabsf(attr[e]);
      int b = c >> SH;
      int loc = atomicAdd(&hist[b], 1);
      u32 lo = (u32)r | ((u32)(c & (BCOLS - 1)) << 20);
      epay[base[b] + loc] = ((u64)__float_as_uint(w) << 32) | lo;
    }
  }
}

// ---------------- per-bucket counting sort (LDS-staged) -> sorted payload + offs/ends + dinv ----------------
__global__ __launch_bounds__(256) void k_sort(const u64* __restrict__ epay,
                                              const int* __restrict__ gcur,
                                              u64* __restrict__ epay2,
                                              int* __restrict__ offs,
                                              int* __restrict__ ends,
                                              float* __restrict__ dinv) {
  __shared__ float ws[BCOLS];
  __shared__ int cnt[BCOLS];
  __shared__ int cur[BCOLS];
  __shared__ u64 stg[BSLOT];   // 36.8 KB staged sorted bucket
  int b = blockIdx.x, tid = threadIdx.x;
  if (tid < BCOLS) { ws[tid] = 0.f; cnt[tid] = 0; }
  __syncthreads();
  int n = gcur[b];
  int e0 = b * BSLOT;
  for (int i = tid; i < n; i += 256) {
    u64 p = epay[e0 + i];
    float w = __uint_as_float((u32)(p >> 32));
    int c7 = ((u32)p >> 20) & (BCOLS - 1);
    atomicAdd(&cnt[c7], 1);
    atomicAdd(&ws[c7], w);
  }
  __syncthreads();
  if (tid < 64) {  // exclusive scan of cnt[128] on wave 0
    int a0 = cnt[tid * 2], a1 = cnt[tid * 2 + 1];
    int s = a0 + a1;
    int t = s;
    #pragma unroll
    for (int d = 1; d < 64; d <<= 1) { int u = __shfl_up(t, d); if (tid >= d) t += u; }
    int excl = t - s;
    cur[tid * 2] = excl;
    cur[tid * 2 + 1] = excl + a0;
  }
  __syncthreads();
  if (tid < BCOLS) {
    int node = b * BCOLS + tid;
    if (node < NN) {
      int st = e0 + cur[tid];
      offs[node] = st;
      ends[node] = st + cnt[tid];
      dinv[node] = 1.0f / sqrtf(ws[tid] + 1.0f);
    }
  }
  __syncthreads();
  // scatter into LDS (node-sorted within bucket)
  for (int i = tid; i < n; i += 256) {
    u64 p = epay[e0 + i];
    int c7 = ((u32)p >> 20) & (BCOLS - 1);
    int loc = atomicAdd(&cur[c7], 1);
    stg[loc] = (p & 0xFFFFFFFF00000000ull) | ((u32)p & 0xFFFFF);
  }
  __syncthreads();
  // coalesced flush
  for (int i = tid; i < n; i += 256) epay2[e0 + i] = stg[i];
}

// ---------------- fp32 GEMM (128-node blocks), bf16 output scaled by dinv ----------------
__global__ __launch_bounds__(256) void k_gemm(const float* __restrict__ A,
                                              const float* __restrict__ B,
                                              u16* __restrict__ C, int M, int K,
                                              const float* __restrict__ dscale) {
  __shared__ float As[8][128];
  __shared__ float Bs[8][64];
  int tid = threadIdx.x;
  int ng = tid >> 4;      // 0..15 -> 8 nodes each
  int cg = tid & 15;      // 0..15 -> 4 cols each
  int nbase = blockIdx.x * 128;
  float acc[8][4];
  #pragma unroll
  for (int i = 0; i < 8; i++)
    #pragma unroll
    for (int j = 0; j < 4; j++) acc[i][j] = 0.f;

  int arow = nbase + (tid >> 1);
  int acl = (tid & 1) * 4;
  int ar = arow < M ? arow : M - 1;

  for (int k0 = 0; k0 < K; k0 += 8) {
    float4 av = *(const float4*)(A + (size_t)ar * K + k0 + acl);
    float2 bv = ((const float2*)(B + (size_t)k0 * 64))[tid];
    __syncthreads();
    As[acl + 0][tid >> 1] = av.x;
    As[acl + 1][tid >> 1] = av.y;
    As[acl + 2][tid >> 1] = av.z;
    As[acl + 3][tid >> 1] = av.w;
    ((float2*)Bs)[tid] = bv;
    __syncthreads();
    #pragma unroll
    for (int k = 0; k < 8; k++) {
      float a[8], bb[4];
      *(float4*)(a)     = *(const float4*)&As[k][ng * 8];
      *(float4*)(a + 4) = *(const float4*)&As[k][ng * 8 + 4];
      *(float4*)(bb)    = *(const float4*)&Bs[k][cg * 4];
      #pragma unroll
      for (int i = 0; i < 8; i++)
        #pragma unroll
        for (int j = 0; j < 4; j++) acc[i][j] += a[i] * bb[j];
    }
  }
  #pragma unroll
  for (int i = 0; i < 8; i++) {
    int n = nbase + ng * 8 + i;
    if (n < M) {
      float dv = dscale[n];
      ushort4 o;
      o.x = f2bf(acc[i][0] * dv);
      o.y = f2bf(acc[i][1] * dv);
      o.z = f2bf(acc[i][2] * dv);
      o.w = f2bf(acc[i][3] * dv);
      *(ushort4*)(C + (size_t)n * 64 + cg * 4) = o;
    }
  }
}

// ---------------- CSR aggregation, half-wave per node (2 ch/lane, 16 edges in flight/wave) ----------------
template<int POOL>
__global__ void k_agg(const u16* __restrict__ g, const int* __restrict__ offs,
                      const int* __restrict__ ends,
                      const u64* __restrict__ epay2,
                      const float* __restrict__ dinv, const float* __restrict__ bias,
                      const int* __restrict__ batch,
                      float* __restrict__ outp) {
  int tid = threadIdx.x;
  int node = blockIdx.x * 8 + ((tid >> 6) << 1) + ((tid >> 5) & 1);
  int sl = tid & 31;                 // 32 lanes per node, 2 channels each
  const u32* g32 = (const u32*)g;    // row r at g32[r*32 + sl]
  int e0 = offs[node], e1 = ends[node];
  float acc0 = 0.f, acc1 = 0.f;
  int e = e0;
  for (; e + 8 <= e1; e += 8) {
    u64 p0 = epay2[e],     p1 = epay2[e + 1];
    u64 p2 = epay2[e + 2], p3 = epay2[e + 3];
    u64 p4 = epay2[e + 4], p5 = epay2[e + 5];
    u64 p6 = epay2[e + 6], p7 = epay2[e + 7];
    u32 v0 = g32[(size_t)((u32)p0 & 0xFFFFF) * 32 + sl];
    u32 v1 = g32[(size_t)((u32)p1 & 0xFFFFF) * 32 + sl];
    u32 v2 = g32[(size_t)((u32)p2 & 0xFFFFF) * 32 + sl];
    u32 v3 = g32[(size_t)((u32)p3 & 0xFFFFF) * 32 + sl];
    u32 v4 = g32[(size_t)((u32)p4 & 0xFFFFF) * 32 + sl];
    u32 v5 = g32[(size_t)((u32)p5 & 0xFFFFF) * 32 + sl];
    u32 v6 = g32[(size_t)((u32)p6 & 0xFFFFF) * 32 + sl];
    u32 v7 = g32[(size_t)((u32)p7 & 0xFFFFF) * 32 + sl];
    float w0 = __uint_as_float((u32)(p0 >> 32));
    float w1 = __uint_as_float((u32)(p1 >> 32));
    float w2 = __uint_as_float((u32)(p2 >> 32));
    float w3 = __uint_as_float((u32)(p3 >> 32));
    float w4 = __uint_as_float((u32)(p4 >> 32));
    float w5 = __uint_as_float((u32)(p5 >> 32));
    float w6 = __uint_as_float((u32)(p6 >> 32));
    float w7 = __uint_as_float((u32)(p7 >> 32));
    acc0 += w0 * bf2f((u16)v0); acc1 += w0 * bf2f((u16)(v0 >> 16));
    acc0 += w1 * bf2f((u16)v1); acc1 += w1 * bf2f((u16)(v1 >> 16));
    acc0 += w2 * bf2f((u16)v2); acc1 += w2 * bf2f((u16)(v2 >> 16));
    acc0 += w3 * bf2f((u16)v3); acc1 += w3 * bf2f((u16)(v3 >> 16));
    acc0 += w4 * bf2f((u16)v4); acc1 += w4 * bf2f((u16)(v4 >> 16));
    acc0 += w5 * bf2f((u16)v5); acc1 += w5 * bf2f((u16)(v5 >> 16));
    acc0 += w6 * bf2f((u16)v6); acc1 += w6 * bf2f((u16)(v6 >> 16));
    acc0 += w7 * bf2f((u16)v7); acc1 += w7 * bf2f((u16)(v7 >> 16));
  }
  for (; e < e1; ++e) {
    u64 p = epay2[e];
    u32 v = g32[(size_t)((u32)p & 0xFFFFF) * 32 + sl];
    float w = __uint_as_float((u32)(p >> 32));
    acc0 += w * bf2f((u16)v); acc1 += w * bf2f((u16)(v >> 16));
  }
  u32 sv = g32[(size_t)node * 32 + sl];
  float dv = dinv[node];
  float2 bv = ((const float2*)bias)[sl];
  float o0 = fmaxf((acc0 + bf2f((u16)sv)) * dv + bv.x, 0.f);
  float o1 = fmaxf((acc1 + bf2f((u16)(sv >> 16))) * dv + bv.y, 0.f);
  if (POOL) {
    float* dst = &outp[batch[node] * 64 + sl * 2];
    atomicAdd(dst, o0);
    atomicAdd(dst + 1, o1);
  } else {
    ((float2*)(outp + (size_t)node * 64))[sl] = make_float2(o0, o1);
  }
}

// ---------------- MLP head: one block per graph; count via binary search on sorted batch ----------------
__global__ __launch_bounds__(256) void k_mlp(const float* __restrict__ pooled,
                                             const int* __restrict__ batch,
                                             const float* __restrict__ L1, const float* __restrict__ c1,
                                             const float* __restrict__ L2, const float* __restrict__ c2,
                                             float* __restrict__ out) {
  __shared__ float m[64];
  __shared__ float xf[200];
  __shared__ float red[8];
  __shared__ float cnts;
  int g = blockIdx.x, tid = threadIdx.x;
  if (tid == 0) {
    int lo = 0, hi = NN;
    while (lo < hi) { int mid = (lo + hi) >> 1; if (batch[mid] < g) lo = mid + 1; else hi = mid; }
    int l0 = lo;
    hi = NN;
    while (lo < hi) { int mid = (lo + hi) >> 1; if (batch[mid] < g + 1) lo = mid + 1; else hi = mid; }
    cnts = fmaxf((float)(lo - l0), 1.f);
  }
  __syncthreads();
  if (tid < 64) m[tid] = pooled[g * 64 + tid] / cnts;
  __syncthreads();
  if (tid < 200) {
    float a = c1[tid];
    #pragma unroll
    for (int k = 0; k < 64; k++) a += m[k] * L1[k * 200 + tid];
    xf[tid] = fmaxf(a, 0.f);
  }
  __syncthreads();
  float p0 = 0.f, p1 = 0.f;
  if (tid < 200) {
    float v = xf[tid];
    p0 = v * L2[tid * 2];
    p1 = v * L2[tid * 2 + 1];
  }
  #pragma unroll
  for (int d = 32; d > 0; d >>= 1) { p0 += __shfl_down(p0, d); p1 += __shfl_down(p1, d); }
  int lane = tid & 63, wid = tid >> 6;
  if (lane == 0) { red[wid * 2] = p0; red[wid * 2 + 1] = p1; }
  __syncthreads();
  if (tid == 0) {
    out[g * 2 + 0] = red[0] + red[2] + red[4] + red[6] + c2[0];
    out[g * 2 + 1] = red[1] + red[3] + red[5] + red[7] + c2[1];
  }
}

// ---------------- launch ----------------
extern "C" void kernel_launch(void* const* d_in, const int* in_sizes, int n_in,
                              void* d_out, int out_size, void* d_ws, size_t ws_size,
                              hipStream_t stream) {
  (void)in_sizes; (void)n_in; (void)out_size; (void)ws_size;
  const float* x    = (const float*)d_in[0];
  const int*   ei   = (const int*)d_in[1];
  const float* attr = (const float*)d_in[2];
  const int*   batch= (const int*)d_in[3];
  const float* W1   = (const float*)d_in[4];
  const float* b1   = (const float*)d_in[5];
  const float* W2   = (const float*)d_in[6];
  const float* b2   = (const float*)d_in[7];
  const float* L1   = (const float*)d_in[8];
  const float* c1   = (const float*)d_in[9];
  const float* L2   = (const float*)d_in[10];
  const float* c2   = (const float*)d_in[11];
  float* out = (float*)d_out;

  char* p = (char*)d_ws;
  auto alloc = [&](size_t bytes) -> void* {
    void* r = (void*)p;
    p += (bytes + 511) & ~(size_t)511;
    return r;
  };
  // epay (bucket regions, dead after k_sort) aliases g1b (bf16, first written by k_gemm)
  u64* epay = (u64*)alloc((size_t)NB * BSLOT * 8);   // 28.8 MB
  u16* g1b  = (u16*)epay;                            // alias (needs 12.8 MB)
  u64* epay2 = (u64*)alloc((size_t)NB * BSLOT * 8);  // 28.8 MB
  float* h1   = (float*)alloc((size_t)NN * 64 * 4);  // fp32 h1
  u16*   g2b  = (u16*)alloc((size_t)NN * 64 * 2);    // bf16 g2
  int*   offs = (int*)alloc((size_t)NN * 4);
  int*   ends = (int*)alloc((size_t)NN * 4);
  float* dinv = (float*)alloc((size_t)NN * 4);
  int*   gcur = (int*)alloc((size_t)NB * 4);         // | contiguous zero region
  float* pooled = (float*)alloc((size_t)NG * 64 * 4);// |

  size_t zspan = (size_t)((char*)pooled + (size_t)NG * 64 * 4 - (char*)gcur);
  hipMemsetAsync(gcur, 0, zspan, stream);

  // build: bucket partition (fixed regions) + per-bucket counting sort
  k_part<<<391, 256, 0, stream>>>(ei, attr, gcur, epay);
  k_sort<<<NB, 256, 0, stream>>>(epay, gcur, epay2, offs, ends, dinv);

  // layer 1: g1 = bf16(dinv .* (x @ W1)); h1 = relu(dinv_c*(sum w*g1[r] + g1[c]) + b1)
  k_gemm<<<782, 256, 0, stream>>>(x, W1, g1b, NN, INCH, dinv);
  k_agg<0><<<NN / 8, 256, 0, stream>>>(g1b, offs, ends, epay2, dinv, b1, batch, h1);
  // layer 2: g2 = bf16(dinv .* (h1 @ W2)); agg fused with pooling accumulate
  k_gemm<<<782, 256, 0, stream>>>(h1, W2, g2b, NN, HID, dinv);
  k_agg<1><<<NN / 8, 256, 0, stream>>>(g2b, offs, ends, epay2, dinv, b2, batch, pooled);

  // head
  k_mlp<<<NG, 256, 0, stream>>>(pooled, batch, L1, c1, L2, c2, out);
}

// Round 10
// 461.516 us; speedup vs baseline: 1.2823x; 1.1712x over previous
//
#include <hip/hip_runtime.h>

#define NN 100000
#define NE 3200000
#define INCH 200
#define HID 64
#define NG 500
#define SH 7
#define BCOLS 128
#define NB 782      // ceil(NN / BCOLS)
#define BSLOT 4608  // fixed slots per bucket (mean 4092, ~8 sigma margin)

typedef unsigned long long u64;
typedef unsigned short u16;
typedef unsigned int u32;

__device__ __forceinline__ float bf2f(u16 v) { return __uint_as_float(((u32)v) << 16); }
__device__ __forceinline__ u16 f2bf(float f) {
  u32 u = __float_as_uint(f);
  u += 0x7FFF + ((u >> 16) & 1);   // round-nearest-even
  return (u16)(u >> 16);
}

// ---------------- partition edges into fixed bucket regions ----------------
__global__ __launch_bounds__(256) void k_part(const int* __restrict__ ei,
                                              const float* __restrict__ attr,
                                              int* __restrict__ gcur,
                                              u64* __restrict__ epay) {
  __shared__ int hist[NB];
  __shared__ int base[NB];
  int tid = threadIdx.x;
  for (int i = tid; i < NB; i += 256) hist[i] = 0;
  __syncthreads();
  int eb = blockIdx.x * 8192;
  int cols[32];
  for (int i = 0; i < 32; ++i) {
    int e = eb + i * 256 + tid;
    int c = (e < NE) ? ei[NE + e] : -1;
    cols[i] = c;
    if (c >= 0) atomicAdd(&hist[c >> SH], 1);
  }
  __syncthreads();
  for (int i = tid; i < NB; i += 256) {
    int v = hist[i];
    base[i] = v ? (atomicAdd(&gcur[i], v) + i * BSLOT) : 0;
    hist[i] = 0;
  }
  __syncthreads();
  for (int i = 0; i < 32; ++i) {
    int c = cols[i];
    if (c >= 0) {
      int e = eb + i * 256 + tid;
      int r = ei[e];
      float w = fabsf(attr[e]);
      int b = c >> SH;
      int loc = atomicAdd(&hist[b], 1);
      u32 lo = (u32)r | ((u32)(c & (BCOLS - 1)) << 20);
      epay[base[b] + loc] = ((u64)__float_as_uint(w) << 32) | lo;
    }
  }
}

// ---------------- per-bucket counting sort (LDS-staged) -> sorted payload + offs/ends + dinv ----------------
__global__ __launch_bounds__(256) void k_sort(const u64* __restrict__ epay,
                                              const int* __restrict__ gcur,
                                              u64* __restrict__ epay2,
                                              int* __restrict__ offs,
                                              int* __restrict__ ends,
                                              float* __restrict__ dinv) {
  __shared__ float ws[BCOLS];
  __shared__ int cnt[BCOLS];
  __shared__ int cur[BCOLS];
  __shared__ u64 stg[BSLOT];   // 36.8 KB staged sorted bucket
  int b = blockIdx.x, tid = threadIdx.x;
  if (tid < BCOLS) { ws[tid] = 0.f; cnt[tid] = 0; }
  __syncthreads();
  int n = gcur[b];
  int e0 = b * BSLOT;
  for (int i = tid; i < n; i += 256) {
    u64 p = epay[e0 + i];
    float w = __uint_as_float((u32)(p >> 32));
    int c7 = ((u32)p >> 20) & (BCOLS - 1);
    atomicAdd(&cnt[c7], 1);
    atomicAdd(&ws[c7], w);
  }
  __syncthreads();
  if (tid < 64) {  // exclusive scan of cnt[128] on wave 0
    int a0 = cnt[tid * 2], a1 = cnt[tid * 2 + 1];
    int s = a0 + a1;
    int t = s;
    #pragma unroll
    for (int d = 1; d < 64; d <<= 1) { int u = __shfl_up(t, d); if (tid >= d) t += u; }
    int excl = t - s;
    cur[tid * 2] = excl;
    cur[tid * 2 + 1] = excl + a0;
  }
  __syncthreads();
  if (tid < BCOLS) {
    int node = b * BCOLS + tid;
    if (node < NN) {
      int st = e0 + cur[tid];
      offs[node] = st;
      ends[node] = st + cnt[tid];
      dinv[node] = 1.0f / sqrtf(ws[tid] + 1.0f);
    }
  }
  __syncthreads();
  // scatter into LDS (node-sorted within bucket)
  for (int i = tid; i < n; i += 256) {
    u64 p = epay[e0 + i];
    int c7 = ((u32)p >> 20) & (BCOLS - 1);
    int loc = atomicAdd(&cur[c7], 1);
    stg[loc] = (p & 0xFFFFFFFF00000000ull) | ((u32)p & 0xFFFFF);
  }
  __syncthreads();
  // coalesced flush
  for (int i = tid; i < n; i += 256) epay2[e0 + i] = stg[i];
}

// ---------------- fp32/bf16-A GEMM (128-node blocks), bf16 output scaled by dinv ----------------
template<int ABF>
__global__ __launch_bounds__(256) void k_gemm(const void* __restrict__ Av,
                                              const float* __restrict__ B,
                                              u16* __restrict__ C, int M, int K,
                                              const float* __restrict__ dscale) {
  __shared__ float As[8][128];
  __shared__ float Bs[8][64];
  const float* Af = (const float*)Av;
  const u16*   Ab = (const u16*)Av;
  int tid = threadIdx.x;
  int ng = tid >> 4;      // 0..15 -> 8 nodes each
  int cg = tid & 15;      // 0..15 -> 4 cols each
  int nbase = blockIdx.x * 128;
  float acc[8][4];
  #pragma unroll
  for (int i = 0; i < 8; i++)
    #pragma unroll
    for (int j = 0; j < 4; j++) acc[i][j] = 0.f;

  int arow = nbase + (tid >> 1);
  int acl = (tid & 1) * 4;
  int ar = arow < M ? arow : M - 1;

  for (int k0 = 0; k0 < K; k0 += 8) {
    float4 av;
    if (ABF) {
      ushort4 q = *(const ushort4*)(Ab + (size_t)ar * K + k0 + acl);
      av = make_float4(bf2f(q.x), bf2f(q.y), bf2f(q.z), bf2f(q.w));
    } else {
      av = *(const float4*)(Af + (size_t)ar * K + k0 + acl);
    }
    float2 bv = ((const float2*)(B + (size_t)k0 * 64))[tid];
    __syncthreads();
    As[acl + 0][tid >> 1] = av.x;
    As[acl + 1][tid >> 1] = av.y;
    As[acl + 2][tid >> 1] = av.z;
    As[acl + 3][tid >> 1] = av.w;
    ((float2*)Bs)[tid] = bv;
    __syncthreads();
    #pragma unroll
    for (int k = 0; k < 8; k++) {
      float a[8], bb[4];
      *(float4*)(a)     = *(const float4*)&As[k][ng * 8];
      *(float4*)(a + 4) = *(const float4*)&As[k][ng * 8 + 4];
      *(float4*)(bb)    = *(const float4*)&Bs[k][cg * 4];
      #pragma unroll
      for (int i = 0; i < 8; i++)
        #pragma unroll
        for (int j = 0; j < 4; j++) acc[i][j] += a[i] * bb[j];
    }
  }
  #pragma unroll
  for (int i = 0; i < 8; i++) {
    int n = nbase + ng * 8 + i;
    if (n < M) {
      float dv = dscale[n];
      ushort4 o;
      o.x = f2bf(acc[i][0] * dv);
      o.y = f2bf(acc[i][1] * dv);
      o.z = f2bf(acc[i][2] * dv);
      o.w = f2bf(acc[i][3] * dv);
      *(ushort4*)(C + (size_t)n * 64 + cg * 4) = o;
    }
  }
}

// ---------------- CSR aggregation (full wave per node, unroll 16) ----------------
// POOL=0: writes bf16 h; POOL=1: fp32 atomic accumulate into pooled
template<int POOL>
__global__ void k_agg(const u16* __restrict__ g, const int* __restrict__ offs,
                      const int* __restrict__ ends,
                      const u64* __restrict__ epay2,
                      const float* __restrict__ dinv, const float* __restrict__ bias,
                      const int* __restrict__ batch,
                      void* __restrict__ outp) {
  int node = blockIdx.x * 4 + (threadIdx.x >> 6);
  int lane = threadIdx.x & 63;
  int e0 = __builtin_amdgcn_readfirstlane(offs[node]);
  int e1 = __builtin_amdgcn_readfirstlane(ends[node]);
  float acc = 0.f;
  int e = e0;
  for (; e + 16 <= e1; e += 16) {
    u64 p[16]; u16 v[16];
    #pragma unroll
    for (int i = 0; i < 16; i++) p[i] = epay2[e + i];
    #pragma unroll
    for (int i = 0; i < 16; i++) v[i] = g[(size_t)((u32)p[i] & 0xFFFFF) * 64 + lane];
    #pragma unroll
    for (int i = 0; i < 16; i++) acc += __uint_as_float((u32)(p[i] >> 32)) * bf2f(v[i]);
  }
  for (; e + 4 <= e1; e += 4) {
    u64 p[4]; u16 v[4];
    #pragma unroll
    for (int i = 0; i < 4; i++) p[i] = epay2[e + i];
    #pragma unroll
    for (int i = 0; i < 4; i++) v[i] = g[(size_t)((u32)p[i] & 0xFFFFF) * 64 + lane];
    #pragma unroll
    for (int i = 0; i < 4; i++) acc += __uint_as_float((u32)(p[i] >> 32)) * bf2f(v[i]);
  }
  for (; e < e1; ++e) {
    u64 p = epay2[e];
    acc += __uint_as_float((u32)(p >> 32)) * bf2f(g[(size_t)((u32)p & 0xFFFFF) * 64 + lane]);
  }
  float v = (acc + bf2f(g[(size_t)node * 64 + lane])) * dinv[node] + bias[lane];
  v = fmaxf(v, 0.f);
  if (POOL) {
    atomicAdd(&((float*)outp)[batch[node] * 64 + lane], v);
  } else {
    ((u16*)outp)[(size_t)node * 64 + lane] = f2bf(v);
  }
}

// ---------------- MLP head: one block per graph; count via binary search on sorted batch ----------------
__global__ __launch_bounds__(256) void k_mlp(const float* __restrict__ pooled,
                                             const int* __restrict__ batch,
                                             const float* __restrict__ L1, const float* __restrict__ c1,
                                             const float* __restrict__ L2, const float* __restrict__ c2,
                                             float* __restrict__ out) {
  __shared__ float m[64];
  __shared__ float xf[200];
  __shared__ float red[8];
  __shared__ float cnts;
  int g = blockIdx.x, tid = threadIdx.x;
  if (tid == 0) {
    int lo = 0, hi = NN;
    while (lo < hi) { int mid = (lo + hi) >> 1; if (batch[mid] < g) lo = mid + 1; else hi = mid; }
    int l0 = lo;
    hi = NN;
    while (lo < hi) { int mid = (lo + hi) >> 1; if (batch[mid] < g + 1) lo = mid + 1; else hi = mid; }
    cnts = fmaxf((float)(lo - l0), 1.f);
  }
  __syncthreads();
  if (tid < 64) m[tid] = pooled[g * 64 + tid] / cnts;
  __syncthreads();
  if (tid < 200) {
    float a = c1[tid];
    #pragma unroll
    for (int k = 0; k < 64; k++) a += m[k] * L1[k * 200 + tid];
    xf[tid] = fmaxf(a, 0.f);
  }
  __syncthreads();
  float p0 = 0.f, p1 = 0.f;
  if (tid < 200) {
    float v = xf[tid];
    p0 = v * L2[tid * 2];
    p1 = v * L2[tid * 2 + 1];
  }
  #pragma unroll
  for (int d = 32; d > 0; d >>= 1) { p0 += __shfl_down(p0, d); p1 += __shfl_down(p1, d); }
  int lane = tid & 63, wid = tid >> 6;
  if (lane == 0) { red[wid * 2] = p0; red[wid * 2 + 1] = p1; }
  __syncthreads();
  if (tid == 0) {
    out[g * 2 + 0] = red[0] + red[2] + red[4] + red[6] + c2[0];
    out[g * 2 + 1] = red[1] + red[3] + red[5] + red[7] + c2[1];
  }
}

// ---------------- launch ----------------
extern "C" void kernel_launch(void* const* d_in, const int* in_sizes, int n_in,
                              void* d_out, int out_size, void* d_ws, size_t ws_size,
                              hipStream_t stream) {
  (void)in_sizes; (void)n_in; (void)out_size; (void)ws_size;
  const float* x    = (const float*)d_in[0];
  const int*   ei   = (const int*)d_in[1];
  const float* attr = (const float*)d_in[2];
  const int*   batch= (const int*)d_in[3];
  const float* W1   = (const float*)d_in[4];
  const float* b1   = (const float*)d_in[5];
  const float* W2   = (const float*)d_in[6];
  const float* b2   = (const float*)d_in[7];
  const float* L1   = (const float*)d_in[8];
  const float* c1   = (const float*)d_in[9];
  const float* L2   = (const float*)d_in[10];
  const float* c2   = (const float*)d_in[11];
  float* out = (float*)d_out;

  char* p = (char*)d_ws;
  auto alloc = [&](size_t bytes) -> void* {
    void* r = (void*)p;
    p += (bytes + 511) & ~(size_t)511;
    return r;
  };
  // epay (bucket regions, dead after k_sort) aliases g1b (bf16, first written by k_gemm)
  u64* epay = (u64*)alloc((size_t)NB * BSLOT * 8);   // 28.8 MB
  u16* g1b  = (u16*)epay;                            // alias (needs 12.8 MB)
  u64* epay2 = (u64*)alloc((size_t)NB * BSLOT * 8);  // 28.8 MB
  u16*   h1b  = (u16*)alloc((size_t)NN * 64 * 2);    // bf16 h1
  u16*   g2b  = (u16*)alloc((size_t)NN * 64 * 2);    // bf16 g2
  int*   offs = (int*)alloc((size_t)NN * 4);
  int*   ends = (int*)alloc((size_t)NN * 4);
  float* dinv = (float*)alloc((size_t)NN * 4);
  int*   gcur = (int*)alloc((size_t)NB * 4);         // | contiguous zero region
  float* pooled = (float*)alloc((size_t)NG * 64 * 4);// |

  size_t zspan = (size_t)((char*)pooled + (size_t)NG * 64 * 4 - (char*)gcur);
  hipMemsetAsync(gcur, 0, zspan, stream);

  // build: bucket partition (fixed regions) + per-bucket counting sort
  k_part<<<391, 256, 0, stream>>>(ei, attr, gcur, epay);
  k_sort<<<NB, 256, 0, stream>>>(epay, gcur, epay2, offs, ends, dinv);

  // layer 1: g1 = bf16(dinv .* (x @ W1)); h1 = bf16(relu(dinv_c*(sum w*g1[r] + g1[c]) + b1))
  k_gemm<0><<<782, 256, 0, stream>>>(x, W1, g1b, NN, INCH, dinv);
  k_agg<0><<<NN / 4, 256, 0, stream>>>(g1b, offs, ends, epay2, dinv, b1, batch, h1b);
  // layer 2: g2 = bf16(dinv .* (h1 @ W2)); agg fused with pooling accumulate
  k_gemm<1><<<782, 256, 0, stream>>>(h1b, W2, g2b, NN, HID, dinv);
  k_agg<1><<<NN / 4, 256, 0, stream>>>(g2b, offs, ends, epay2, dinv, b2, batch, pooled);

  // head
  k_mlp<<<NG, 256, 0, stream>>>(pooled, batch, L1, c1, L2, c2, out);
}

// Round 11
// 446.587 us; speedup vs baseline: 1.3251x; 1.0334x over previous
//
#include <hip/hip_runtime.h>

#define NN 100000
#define NE 3200000
#define INCH 200
#define HID 64
#define NG 500
#define SH 7
#define BCOLS 128
#define NB 782      // ceil(NN / BCOLS)
#define BSLOT 4608  // fixed slots per bucket (mean 4092, ~8 sigma margin)

typedef unsigned long long u64;
typedef unsigned short u16;
typedef unsigned int u32;

__device__ __forceinline__ float bf2f(u16 v) { return __uint_as_float(((u32)v) << 16); }
__device__ __forceinline__ u16 f2bf(float f) {
  u32 u = __float_as_uint(f);
  u += 0x7FFF + ((u >> 16) & 1);   // round-nearest-even
  return (u16)(u >> 16);
}

// ---------------- partition edges into fixed bucket regions (1024 thr: occupancy) ----------------
__global__ __launch_bounds__(1024) void k_part(const int* __restrict__ ei,
                                               const float* __restrict__ attr,
                                               int* __restrict__ gcur,
                                               u64* __restrict__ epay) {
  __shared__ int hist[NB];
  __shared__ int base[NB];
  int tid = threadIdx.x;
  for (int i = tid; i < NB; i += 1024) hist[i] = 0;
  __syncthreads();
  int eb = blockIdx.x * 8192;
  int cols[8];
  for (int i = 0; i < 8; ++i) {
    int e = eb + i * 1024 + tid;
    int c = (e < NE) ? ei[NE + e] : -1;
    cols[i] = c;
    if (c >= 0) atomicAdd(&hist[c >> SH], 1);
  }
  __syncthreads();
  for (int i = tid; i < NB; i += 1024) {
    int v = hist[i];
    base[i] = v ? (atomicAdd(&gcur[i], v) + i * BSLOT) : 0;
    hist[i] = 0;
  }
  __syncthreads();
  for (int i = 0; i < 8; ++i) {
    int c = cols[i];
    if (c >= 0) {
      int e = eb + i * 1024 + tid;
      int r = ei[e];
      float w = fabsf(attr[e]);
      int b = c >> SH;
      int loc = atomicAdd(&hist[b], 1);
      u32 lo = (u32)r | ((u32)(c & (BCOLS - 1)) << 20);
      epay[base[b] + loc] = ((u64)__float_as_uint(w) << 32) | lo;
    }
  }
}

// ---------------- per-bucket counting sort (LDS-staged) -> sorted payload + offs/ends + dinv ----------------
__global__ __launch_bounds__(256) void k_sort(const u64* __restrict__ epay,
                                              const int* __restrict__ gcur,
                                              u64* __restrict__ epay2,
                                              int* __restrict__ offs,
                                              int* __restrict__ ends,
                                              float* __restrict__ dinv) {
  __shared__ float ws[BCOLS];
  __shared__ int cnt[BCOLS];
  __shared__ int cur[BCOLS];
  __shared__ u64 stg[BSLOT];   // 36.8 KB staged sorted bucket
  int b = blockIdx.x, tid = threadIdx.x;
  if (tid < BCOLS) { ws[tid] = 0.f; cnt[tid] = 0; }
  __syncthreads();
  int n = gcur[b];
  int e0 = b * BSLOT;
  for (int i = tid; i < n; i += 256) {
    u64 p = epay[e0 + i];
    float w = __uint_as_float((u32)(p >> 32));
    int c7 = ((u32)p >> 20) & (BCOLS - 1);
    atomicAdd(&cnt[c7], 1);
    atomicAdd(&ws[c7], w);
  }
  __syncthreads();
  if (tid < 64) {  // exclusive scan of cnt[128] on wave 0
    int a0 = cnt[tid * 2], a1 = cnt[tid * 2 + 1];
    int s = a0 + a1;
    int t = s;
    #pragma unroll
    for (int d = 1; d < 64; d <<= 1) { int u = __shfl_up(t, d); if (tid >= d) t += u; }
    int excl = t - s;
    cur[tid * 2] = excl;
    cur[tid * 2 + 1] = excl + a0;
  }
  __syncthreads();
  if (tid < BCOLS) {
    int node = b * BCOLS + tid;
    if (node < NN) {
      int st = e0 + cur[tid];
      offs[node] = st;
      ends[node] = st + cnt[tid];
      dinv[node] = 1.0f / sqrtf(ws[tid] + 1.0f);
    }
  }
  __syncthreads();
  // scatter into LDS (node-sorted within bucket)
  for (int i = tid; i < n; i += 256) {
    u64 p = epay[e0 + i];
    int c7 = ((u32)p >> 20) & (BCOLS - 1);
    int loc = atomicAdd(&cur[c7], 1);
    stg[loc] = (p & 0xFFFFFFFF00000000ull) | ((u32)p & 0xFFFFF);
  }
  __syncthreads();
  // coalesced flush
  for (int i = tid; i < n; i += 256) epay2[e0 + i] = stg[i];
}

// ---------------- fp32/bf16-A GEMM (128-node blocks), bf16 output scaled by dinv ----------------
template<int ABF>
__global__ __launch_bounds__(256) void k_gemm(const void* __restrict__ Av,
                                              const float* __restrict__ B,
                                              u16* __restrict__ C, int M, int K,
                                              const float* __restrict__ dscale) {
  __shared__ float As[8][128];
  __shared__ float Bs[8][64];
  const float* Af = (const float*)Av;
  const u16*   Ab = (const u16*)Av;
  int tid = threadIdx.x;
  int ng = tid >> 4;      // 0..15 -> 8 nodes each
  int cg = tid & 15;      // 0..15 -> 4 cols each
  int nbase = blockIdx.x * 128;
  float acc[8][4];
  #pragma unroll
  for (int i = 0; i < 8; i++)
    #pragma unroll
    for (int j = 0; j < 4; j++) acc[i][j] = 0.f;

  int arow = nbase + (tid >> 1);
  int acl = (tid & 1) * 4;
  int ar = arow < M ? arow : M - 1;

  for (int k0 = 0; k0 < K; k0 += 8) {
    float4 av;
    if (ABF) {
      ushort4 q = *(const ushort4*)(Ab + (size_t)ar * K + k0 + acl);
      av = make_float4(bf2f(q.x), bf2f(q.y), bf2f(q.z), bf2f(q.w));
    } else {
      av = *(const float4*)(Af + (size_t)ar * K + k0 + acl);
    }
    float2 bv = ((const float2*)(B + (size_t)k0 * 64))[tid];
    __syncthreads();
    As[acl + 0][tid >> 1] = av.x;
    As[acl + 1][tid >> 1] = av.y;
    As[acl + 2][tid >> 1] = av.z;
    As[acl + 3][tid >> 1] = av.w;
    ((float2*)Bs)[tid] = bv;
    __syncthreads();
    #pragma unroll
    for (int k = 0; k < 8; k++) {
      float a[8], bb[4];
      *(float4*)(a)     = *(const float4*)&As[k][ng * 8];
      *(float4*)(a + 4) = *(const float4*)&As[k][ng * 8 + 4];
      *(float4*)(bb)    = *(const float4*)&Bs[k][cg * 4];
      #pragma unroll
      for (int i = 0; i < 8; i++)
        #pragma unroll
        for (int j = 0; j < 4; j++) acc[i][j] += a[i] * bb[j];
    }
  }
  #pragma unroll
  for (int i = 0; i < 8; i++) {
    int n = nbase + ng * 8 + i;
    if (n < M) {
      float dv = dscale[n];
      ushort4 o;
      o.x = f2bf(acc[i][0] * dv);
      o.y = f2bf(acc[i][1] * dv);
      o.z = f2bf(acc[i][2] * dv);
      o.w = f2bf(acc[i][3] * dv);
      *(ushort4*)(C + (size_t)n * 64 + cg * 4) = o;
    }
  }
}

// ---------------- CSR aggregation (full wave per node, unroll 16) ----------------
// POOL=0: writes bf16 h; POOL=1: fp32 atomic accumulate into pooled
template<int POOL>
__global__ void k_agg(const u16* __restrict__ g, const int* __restrict__ offs,
                      const int* __restrict__ ends,
                      const u64* __restrict__ epay2,
                      const float* __restrict__ dinv, const float* __restrict__ bias,
                      const int* __restrict__ batch,
                      void* __restrict__ outp) {
  int node = blockIdx.x * 4 + (threadIdx.x >> 6);
  int lane = threadIdx.x & 63;
  int e0 = __builtin_amdgcn_readfirstlane(offs[node]);
  int e1 = __builtin_amdgcn_readfirstlane(ends[node]);
  float acc = 0.f;
  int e = e0;
  for (; e + 16 <= e1; e += 16) {
    u64 p[16]; u16 v[16];
    #pragma unroll
    for (int i = 0; i < 16; i++) p[i] = epay2[e + i];
    #pragma unroll
    for (int i = 0; i < 16; i++) v[i] = g[(size_t)((u32)p[i] & 0xFFFFF) * 64 + lane];
    #pragma unroll
    for (int i = 0; i < 16; i++) acc += __uint_as_float((u32)(p[i] >> 32)) * bf2f(v[i]);
  }
  for (; e + 4 <= e1; e += 4) {
    u64 p[4]; u16 v[4];
    #pragma unroll
    for (int i = 0; i < 4; i++) p[i] = epay2[e + i];
    #pragma unroll
    for (int i = 0; i < 4; i++) v[i] = g[(size_t)((u32)p[i] & 0xFFFFF) * 64 + lane];
    #pragma unroll
    for (int i = 0; i < 4; i++) acc += __uint_as_float((u32)(p[i] >> 32)) * bf2f(v[i]);
  }
  for (; e < e1; ++e) {
    u64 p = epay2[e];
    acc += __uint_as_float((u32)(p >> 32)) * bf2f(g[(size_t)((u32)p & 0xFFFFF) * 64 + lane]);
  }
  float v = (acc + bf2f(g[(size_t)node * 64 + lane])) * dinv[node] + bias[lane];
  v = fmaxf(v, 0.f);
  if (POOL) {
    atomicAdd(&((float*)outp)[batch[node] * 64 + lane], v);
  } else {
    ((u16*)outp)[(size_t)node * 64 + lane] = f2bf(v);
  }
}

// ---------------- MLP head: one block per graph; count via binary search on sorted batch ----------------
__global__ __launch_bounds__(256) void k_mlp(const float* __restrict__ pooled,
                                             const int* __restrict__ batch,
                                             const float* __restrict__ L1, const float* __restrict__ c1,
                                             const float* __restrict__ L2, const float* __restrict__ c2,
                                             float* __restrict__ out) {
  __shared__ float m[64];
  __shared__ float xf[200];
  __shared__ float red[8];
  __shared__ float cnts;
  int g = blockIdx.x, tid = threadIdx.x;
  if (tid == 0) {
    int lo = 0, hi = NN;
    while (lo < hi) { int mid = (lo + hi) >> 1; if (batch[mid] < g) lo = mid + 1; else hi = mid; }
    int l0 = lo;
    hi = NN;
    while (lo < hi) { int mid = (lo + hi) >> 1; if (batch[mid] < g + 1) lo = mid + 1; else hi = mid; }
    cnts = fmaxf((float)(lo - l0), 1.f);
  }
  __syncthreads();
  if (tid < 64) m[tid] = pooled[g * 64 + tid] / cnts;
  __syncthreads();
  if (tid < 200) {
    float a = c1[tid];
    #pragma unroll
    for (int k = 0; k < 64; k++) a += m[k] * L1[k * 200 + tid];
    xf[tid] = fmaxf(a, 0.f);
  }
  __syncthreads();
  float p0 = 0.f, p1 = 0.f;
  if (tid < 200) {
    float v = xf[tid];
    p0 = v * L2[tid * 2];
    p1 = v * L2[tid * 2 + 1];
  }
  #pragma unroll
  for (int d = 32; d > 0; d >>= 1) { p0 += __shfl_down(p0, d); p1 += __shfl_down(p1, d); }
  int lane = tid & 63, wid = tid >> 6;
  if (lane == 0) { red[wid * 2] = p0; red[wid * 2 + 1] = p1; }
  __syncthreads();
  if (tid == 0) {
    out[g * 2 + 0] = red[0] + red[2] + red[4] + red[6] + c2[0];
    out[g * 2 + 1] = red[1] + red[3] + red[5] + red[7] + c2[1];
  }
}

// ---------------- launch ----------------
extern "C" void kernel_launch(void* const* d_in, const int* in_sizes, int n_in,
                              void* d_out, int out_size, void* d_ws, size_t ws_size,
                              hipStream_t stream) {
  (void)in_sizes; (void)n_in; (void)out_size; (void)ws_size;
  const float* x    = (const float*)d_in[0];
  const int*   ei   = (const int*)d_in[1];
  const float* attr = (const float*)d_in[2];
  const int*   batch= (const int*)d_in[3];
  const float* W1   = (const float*)d_in[4];
  const float* b1   = (const float*)d_in[5];
  const float* W2   = (const float*)d_in[6];
  const float* b2   = (const float*)d_in[7];
  const float* L1   = (const float*)d_in[8];
  const float* c1   = (const float*)d_in[9];
  const float* L2   = (const float*)d_in[10];
  const float* c2   = (const float*)d_in[11];
  float* out = (float*)d_out;

  char* p = (char*)d_ws;
  auto alloc = [&](size_t bytes) -> void* {
    void* r = (void*)p;
    p += (bytes + 511) & ~(size_t)511;
    return r;
  };
  // epay (bucket regions, dead after k_sort) aliases g1b (bf16, first written by k_gemm)
  u64* epay = (u64*)alloc((size_t)NB * BSLOT * 8);   // 28.8 MB
  u16* g1b  = (u16*)epay;                            // alias (needs 12.8 MB)
  u64* epay2 = (u64*)alloc((size_t)NB * BSLOT * 8);  // 28.8 MB
  u16*   h1b  = (u16*)alloc((size_t)NN * 64 * 2);    // bf16 h1
  u16*   g2b  = (u16*)alloc((size_t)NN * 64 * 2);    // bf16 g2
  int*   offs = (int*)alloc((size_t)NN * 4);
  int*   ends = (int*)alloc((size_t)NN * 4);
  float* dinv = (float*)alloc((size_t)NN * 4);
  int*   gcur = (int*)alloc((size_t)NB * 4);         // | contiguous zero region
  float* pooled = (float*)alloc((size_t)NG * 64 * 4);// |

  size_t zspan = (size_t)((char*)pooled + (size_t)NG * 64 * 4 - (char*)gcur);
  hipMemsetAsync(gcur, 0, zspan, stream);

  // build: bucket partition (fixed regions) + per-bucket counting sort
  k_part<<<391, 1024, 0, stream>>>(ei, attr, gcur, epay);
  k_sort<<<NB, 256, 0, stream>>>(epay, gcur, epay2, offs, ends, dinv);

  // layer 1: g1 = bf16(dinv .* (x @ W1)); h1 = bf16(relu(dinv_c*(sum w*g1[r] + g1[c]) + b1))
  k_gemm<0><<<782, 256, 0, stream>>>(x, W1, g1b, NN, INCH, dinv);
  k_agg<0><<<NN / 4, 256, 0, stream>>>(g1b, offs, ends, epay2, dinv, b1, batch, h1b);
  // layer 2: g2 = bf16(dinv .* (h1 @ W2)); agg fused with pooling accumulate
  k_gemm<1><<<782, 256, 0, stream>>>(h1b, W2, g2b, NN, HID, dinv);
  k_agg<1><<<NN / 4, 256, 0, stream>>>(g2b, offs, ends, epay2, dinv, b2, batch, pooled);

  // head
  k_mlp<<<NG, 256, 0, stream>>>(pooled, batch, L1, c1, L2, c2, out);
}